// Round 10
// baseline (268.881 us; speedup 1.0000x reference)
//
#include <hip/hip_runtime.h>
#include <hip/hip_bf16.h>
#include <math.h>

// Problem constants
#define BATCH 16
#define SEG 1024
#define DMODEL 256
#define NH 8
#define DK 32
#define DFF 1024
#define NTOK (BATCH * 2 * SEG)        // 32768 tokens
#define EPS 1e-5f

typedef __attribute__((ext_vector_type(8))) short short8;
typedef __attribute__((ext_vector_type(4))) short short4b;
typedef __attribute__((ext_vector_type(4))) float f32x4;

#if __has_builtin(__builtin_amdgcn_exp2f)
#define EXP2(x) __builtin_amdgcn_exp2f(x)
#else
#define EXP2(x) __expf((x) * 0.6931471805599453f)
#endif

__device__ __forceinline__ ushort f2bf(float x) {
    union { float f; unsigned u; } a; a.f = x;
    unsigned r = a.u + 0x7fffu + ((a.u >> 16) & 1u);   // RNE
    return (ushort)(r >> 16);
}

// async global -> LDS, 16 B per lane. lds base must be wave-uniform;
// HW writes lane i's 16 B at lds_base + i*16.
typedef const __attribute__((address_space(1))) unsigned gas_u32;
typedef __attribute__((address_space(3))) unsigned las_u32;
__device__ __forceinline__ void gload_lds16(const ushort* g, ushort* l) {
    __builtin_amdgcn_global_load_lds((gas_u32*)g, (las_u32*)l, 16, 0, 0);
}

// ---------------------------------------------------------------------------
// Merged weight fragmentizer: all 6 weights in ONE launch (384 blocks).
// ---------------------------------------------------------------------------
__global__ __launch_bounds__(256) void wfrag_all_kernel(
    const float* __restrict__ Wq, const float* __restrict__ Wk,
    const float* __restrict__ Wv, const float* __restrict__ Wo,
    const float* __restrict__ W1, const float* __restrict__ W2,
    ushort* __restrict__ Wqf, ushort* __restrict__ Wkf,
    ushort* __restrict__ Wvf, ushort* __restrict__ Wof,
    ushort* __restrict__ W1f, ushort* __restrict__ W2f)
{
    const int blk = blockIdx.x;          // 0..383
    const float* src; ushort* dst; int K, N, order, base;
    if (blk < 32)       { src = Wq; dst = Wqf; K = 256;  N = 256;  order = 0; base = 0;   }
    else if (blk < 64)  { src = Wk; dst = Wkf; K = 256;  N = 256;  order = 0; base = 32;  }
    else if (blk < 96)  { src = Wv; dst = Wvf; K = 256;  N = 256;  order = 0; base = 64;  }
    else if (blk < 128) { src = Wo; dst = Wof; K = 256;  N = 256;  order = 0; base = 96;  }
    else if (blk < 256) { src = W1; dst = W1f; K = 256;  N = 1024; order = 0; base = 128; }
    else                { src = W2; dst = W2f; K = 1024; N = 256;  order = 1; base = 256; }
    const int tid = (blk - base) * 256 + threadIdx.x;
    const int KT_ = K >> 5, NT_ = N >> 4;
    const int lane = tid & 63;
    const int frag = tid >> 6;
    int kt, nt;
    if (order) { kt = frag / NT_; nt = frag % NT_; }
    else       { nt = frag / KT_; kt = frag % KT_; }
    const int quad = lane >> 4, l = lane & 15;
    const float* s = src + (size_t)(kt * 32 + quad * 8) * N + nt * 16 + l;
    short8 v;
#pragma unroll
    for (int j = 0; j < 8; j++) v[j] = (short)f2bf(s[(size_t)j * N]);
    *(short8*)&dst[(size_t)tid * 8] = v;
}

#define ASTR 264   // LDS A row stride (bf16 units) - conflict-free ds_read_b128

// ---------------------------------------------------------------------------
// Dense pass helper (4-wave blocks): 4 chunks of 64 out-dims; W panel
// double-buffered. WL must hold 2 x 8192 ushorts.
// ---------------------------------------------------------------------------
__device__ __forceinline__ void dense256_pass(
    const ushort* __restrict__ Wf, ushort* WL, const short8* af,
    f32x4* acc, int t, int w, int lane)
{
#pragma unroll
    for (int nt = 0; nt < 16; ++nt) acc[nt] = (f32x4){0.f, 0.f, 0.f, 0.f};
    {
        const ushort* g = Wf + (size_t)w * 4096 + lane * 8;
        ushort* ld = WL + w * 4096;
#pragma unroll
        for (int i = 0; i < 8; ++i) gload_lds16(g + i * 512, ld + i * 512);
    }
    __syncthreads();
    for (int c = 0; c < 4; ++c) {
        if (c < 3) {
            const ushort* g = Wf + (size_t)(c + 1) * 16384 + w * 4096 + lane * 8;
            ushort* ld = WL + ((c + 1) & 1) * 8192 + w * 4096;
#pragma unroll
            for (int i = 0; i < 8; ++i) gload_lds16(g + i * 512, ld + i * 512);
        }
        const ushort* buf = WL + (c & 1) * 8192;
#pragma unroll
        for (int n2 = 0; n2 < 4; ++n2)
#pragma unroll
            for (int kt = 0; kt < 8; ++kt) {
                const short8 bf_ = *(const short8*)&buf[(n2 * 8 + kt) * 512 + lane * 8];
                acc[c * 4 + n2] = __builtin_amdgcn_mfma_f32_16x16x32_bf16(af[kt], bf_, acc[c * 4 + n2], 0, 0, 0);
            }
        __syncthreads();
    }
}

// ---------------------------------------------------------------------------
// Kernel 1: fused QKV projection, BALANCED 3-way grid (768 blocks).
// ---------------------------------------------------------------------------
__global__ __launch_bounds__(256) void qkv_mfma_kernel(
    const float* __restrict__ x,
    const ushort* __restrict__ Wqf, const float* __restrict__ bq,
    const ushort* __restrict__ Wkf, const float* __restrict__ bk,
    const ushort* __restrict__ Wvf, const float* __restrict__ bv,
    ushort* __restrict__ qbuf, ushort* __restrict__ kbuf,
    ushort* __restrict__ qt, ushort* __restrict__ vt)
{
    __shared__ __align__(16) ushort SM[64 * ASTR];
    const int bid = blockIdx.x;          // 0..767
    const int which = bid >> 8;          // 0=Q, 1=K, 2=V
    const int sub = bid & 255;
    const int b = sub >> 4, ti = sub & 15;
    const int half = (which == 0) ? 0 : 1;
    const int t = threadIdx.x;
    const int w = t >> 6, lane = t & 63, l = lane & 15, quad = lane >> 4;

    const float* xrow = x + ((size_t)b * 2048 + (size_t)half * 1024 + ti * 64) * 256;
#pragma unroll
    for (int p = 0; p < 16; ++p) {
        int ch = t + 256 * p;
        int row = ch >> 6, c4 = ch & 63;
        float4 v = *(const float4*)&xrow[row * 256 + c4 * 4];
        uint2 pk;
        pk.x = (unsigned)f2bf(v.x) | ((unsigned)f2bf(v.y) << 16);
        pk.y = (unsigned)f2bf(v.z) | ((unsigned)f2bf(v.w) << 16);
        *(uint2*)&SM[row * ASTR + c4 * 4] = pk;
    }
    __syncthreads();

    short8 af[8];
#pragma unroll
    for (int kt = 0; kt < 8; ++kt)
        af[kt] = *(const short8*)&SM[(w * 16 + l) * ASTR + kt * 32 + quad * 8];
    __syncthreads();

    const ushort* Wf  = (which == 0) ? Wqf : (which == 1 ? Wkf : Wvf);
    const float* bias = (which == 0) ? bq  : (which == 1 ? bk  : bv);
    const float kscale = (which == 1) ? 0.25503472f : 1.0f;  // sc*log2e

    f32x4 acc[16];
    dense256_pass(Wf, SM, af, acc, t, w, lane);

    ushort bfv[16][4];
#pragma unroll
    for (int nt = 0; nt < 16; ++nt) {
        const float bb = bias[nt * 16 + l];
#pragma unroll
        for (int r = 0; r < 4; ++r) bfv[nt][r] = f2bf((acc[nt][r] + bb) * kscale);
    }

    if (which <= 1) {                 // rowout: Q or K
        ushort* obuf = which ? kbuf : qbuf;
#pragma unroll
        for (int nt = 0; nt < 16; ++nt) {
            const int h = nt >> 1, e = (nt & 1) * 16 + l;
#pragma unroll
            for (int r = 0; r < 4; ++r) {
                int tok = ti * 64 + w * 16 + quad * 4 + r;
                obuf[(((size_t)b * 8 + h) * SEG + tok) * 32 + e] = bfv[nt][r];
            }
        }
    }
    if (which != 1) {                 // trout: Q or V
        ushort* tb = which ? vt : qt;
#pragma unroll
        for (int nt = 0; nt < 16; ++nt)
#pragma unroll
            for (int r = 0; r < 4; ++r)
                SM[(nt * 16 + l) * 66 + w * 16 + quad * 4 + r] = bfv[nt][r];
        __syncthreads();
        const int d = t, hh = t >> 5, e = t & 31;
        ushort* dr = tb + (((size_t)b * 8 + hh) * 32 + e) * 1024 + ti * 64;
#pragma unroll
        for (int j = 0; j < 8; ++j) {
            uint2 v;
            v.x = *(const unsigned*)&SM[d * 66 + j * 8];
            v.y = *(const unsigned*)&SM[d * 66 + j * 8 + 2];
            unsigned z0 = *(const unsigned*)&SM[d * 66 + j * 8 + 4];
            unsigned z1 = *(const unsigned*)&SM[d * 66 + j * 8 + 6];
            *(uint4*)&dr[j * 8] = make_uint4(v.x, v.y, z0, z1);
        }
    }
}

// ---------------------------------------------------------------------------
// Kernel 2: two-stage attention (staged K/V, lane-permuted K write, KP=40/
// VP=132) + T14 async-STAGE split.
// ---------------------------------------------------------------------------
#define KTILE 128
#define KP 40       // Kl row stride
#define VP 132      // Vl row stride over keys

__global__ __launch_bounds__(256) void attn_mfma_kernel(
    const ushort* __restrict__ qbuf, const ushort* __restrict__ kbuf,
    const ushort* __restrict__ qt, const ushort* __restrict__ vt,
    ushort* __restrict__ abuf)
{
    __shared__ __align__(16) ushort Kl[KTILE * KP];   // 10240 B; reused as O-bounce
    __shared__ __align__(16) ushort Vl[32 * VP];      //  8448 B

    const int bid   = blockIdx.x;        // 0 .. 4095
    const int sbh   = bid & 255;
    const int qtile = bid >> 8;
    const int stage = sbh >> 7;
    const int b     = (sbh >> 3) & 15;
    const int h     = sbh & 7;

    const ushort* Qm = stage ? kbuf : qbuf;
    const ushort* Km = stage ? qbuf : kbuf;
    const ushort* Vt = stage ? qt : vt;
    const size_t bh = ((size_t)b * 8 + h) * SEG * 32;

    const int t    = threadIdx.x;
    const int w    = t >> 6;
    const int lane = t & 63;
    const int l    = lane & 15;
    const int quad = lane >> 4;

    const int qrow = qtile * 64 + w * 16 + l;
    const short8 qf = *(const short8*)&Qm[bh + (size_t)qrow * 32 + quad * 8];

    f32x4 o0 = {0.f, 0.f, 0.f, 0.f};
    f32x4 o1 = {0.f, 0.f, 0.f, 0.f};
    f32x4 o2 = {0.f, 0.f, 0.f, 0.f};
    const short4b ones = {(short)0x3F80, (short)0x3F80, (short)0x3F80, (short)0x3F80};

    const int ch0 = t, ch1 = t + 256;
    const int kr0 = ((ch0 >> 6) << 4) | (ch0 & 15), kp0 = (ch0 >> 4) & 3;
    const int kr1 = ((ch1 >> 6) << 4) | (ch1 & 15), kp1 = (ch1 >> 4) & 3;
    const int vd0 = ch0 >> 4, vc0 = ch0 & 15;
    const int vd1 = ch1 >> 4, vc1 = ch1 & 15;
    const ushort* Kgb = &Km[bh];
    const ushort* Vgb = &Vt[bh];

    short8 rk0 = *(const short8*)&Kgb[(size_t)kr0 * 32 + kp0 * 8];
    short8 rk1 = *(const short8*)&Kgb[(size_t)kr1 * 32 + kp1 * 8];
    short8 rv0 = *(const short8*)&Vgb[(size_t)vd0 * 1024 + vc0 * 8];
    short8 rv1 = *(const short8*)&Vgb[(size_t)vd1 * 1024 + vc1 * 8];

    for (int tile = 0; tile < 8; ++tile) {
        __syncthreads();
        *(short8*)&Kl[kr0 * KP + kp0 * 8] = rk0;
        *(short8*)&Kl[kr1 * KP + kp1 * 8] = rk1;
        *(short8*)&Vl[vd0 * VP + vc0 * 8] = rv0;
        *(short8*)&Vl[vd1 * VP + vc1 * 8] = rv1;
        __syncthreads();

        if (tile < 7) {
            const size_t ko = (size_t)(tile + 1) * KTILE * 32;
            const size_t vo = (size_t)(tile + 1) * KTILE;
            rk0 = *(const short8*)&Kgb[ko + (size_t)kr0 * 32 + kp0 * 8];
            rk1 = *(const short8*)&Kgb[ko + (size_t)kr1 * 32 + kp1 * 8];
            rv0 = *(const short8*)&Vgb[vo + (size_t)vd0 * 1024 + vc0 * 8];
            rv1 = *(const short8*)&Vgb[vo + (size_t)vd1 * 1024 + vc1 * 8];
        }

#pragma unroll
        for (int kb = 0; kb < 8; ++kb) {
            const short8 kf = *(const short8*)&Kl[(kb * 16 + l) * KP + quad * 8];
            f32x4 z = {0.f, 0.f, 0.f, 0.f};
            f32x4 sc = __builtin_amdgcn_mfma_f32_16x16x32_bf16(kf, qf, z, 0, 0, 0);
            union { float f; unsigned u; } a0, a1, a2, a3;
            a0.f = EXP2(sc[0]); a1.f = EXP2(sc[1]);
            a2.f = EXP2(sc[2]); a3.f = EXP2(sc[3]);
            unsigned lo = __builtin_amdgcn_perm(a1.u, a0.u, 0x07060302u);
            unsigned hi = __builtin_amdgcn_perm(a3.u, a2.u, 0x07060302u);
            union { uint2 u; short4b s; } pk; pk.u = make_uint2(lo, hi);
            const short4b vf0 = *(const short4b*)&Vl[l * VP + kb * 16 + quad * 4];
            const short4b vf1 = *(const short4b*)&Vl[(16 + l) * VP + kb * 16 + quad * 4];
            o0 = __builtin_amdgcn_mfma_f32_16x16x16bf16_1k(vf0, pk.s, o0, 0, 0, 0);
            o1 = __builtin_amdgcn_mfma_f32_16x16x16bf16_1k(vf1, pk.s, o1, 0, 0, 0);
            o2 = __builtin_amdgcn_mfma_f32_16x16x16bf16_1k(ones, pk.s, o2, 0, 0, 0);
        }
    }

    const float inv = 1.0f / o2[0];
#pragma unroll
    for (int r = 0; r < 4; ++r) { o0[r] *= inv; o1[r] *= inv; }

    __syncthreads();
    ushort* Ob = &Kl[w * 16 * 40];
#pragma unroll
    for (int r = 0; r < 4; ++r) {
        Ob[l * 40 + quad * 4 + r]      = f2bf(o0[r]);
        Ob[l * 40 + 16 + quad * 4 + r] = f2bf(o1[r]);
    }
    __syncthreads();
    const int q = lane >> 2, part = lane & 3;
    const short8 ov = *(const short8*)&Ob[q * 40 + part * 8];
    const int tok = qtile * 64 + w * 16 + q;
    *(short8*)&abuf[((size_t)b * 2 * SEG + (size_t)stage * SEG + tok) * 256 + h * 32 + part * 8] = ov;
}

// ---------------------------------------------------------------------------
// Kernel 3: FUSED proj+LN1+MLP+LN2, v2: 256 blocks x 512 thr x 128 tokens,
// 1 block/CU. Weights streamed ONCE per CU (halves the per-CU staging bytes
// that have bound every variant at ~12 B/cyc/CU). The 1-block latency gap
// (R6) is closed by a 3-DEEP panel pipeline with counted s_waitcnt vmcnt(4)
// (T3/T4): two 4-load batches per wave stay in flight across barriers; vmcnt
// never drains to 0 in the main loop. Phase A (proj) = 8-wave dense pass,
// 2-deep. h stays in registers (LN2 residual) + bf16 in LDS for phase B.
// ---------------------------------------------------------------------------
#define GP 40

__global__ __launch_bounds__(512, 2) void proj_mlp_kernel(
    const ushort* __restrict__ abuf, const ushort* __restrict__ Wof,
    const float* __restrict__ bo, const float* __restrict__ x,
    const float* __restrict__ g31, const float* __restrict__ b31,
    const ushort* __restrict__ W1f, const float* __restrict__ b1,
    const ushort* __restrict__ W2f, const float* __restrict__ b2,
    const float* __restrict__ g41, const float* __restrict__ b41,
    float* __restrict__ io)
{
    __shared__ __align__(16) ushort SM[3 * 16384];   // 96 KB: 3-deep panels / A-overlay
    __shared__ __align__(16) ushort G[8][16 * GP];   // per-wave private GELU buf
    __shared__ __align__(16) float B1L[DFF];          // staged b1
    const int bid = blockIdx.x;          // 0..255
    const size_t tok0 = (size_t)bid * 128;
    const int t = threadIdx.x;
    const int w = t >> 6, lane = t & 63, l = lane & 15, quad = lane >> 4;

    // ---- phase A: stage abuf tile (128 rows) into SM + b1 ----
#pragma unroll
    for (int p = 0; p < 8; ++p) {
        int ch = t + 512 * p;
        int row = ch >> 5, c8 = ch & 31;
        *(short8*)&SM[row * ASTR + c8 * 8] = *(const short8*)&abuf[(tok0 + row) * 256 + c8 * 8];
    }
    *(float2*)&B1L[t * 2] = *(const float2*)&b1[t * 2];
    __syncthreads();

    short8 af[8];
#pragma unroll
    for (int kt = 0; kt < 8; ++kt)
        af[kt] = *(const short8*)&SM[(w * 16 + l) * ASTR + kt * 32 + quad * 8];
    __syncthreads();

    // ---- dense Wo pass, 8 waves, 2-deep (4 chunks of 64 out-dims) ----
    f32x4 acc[16];
#pragma unroll
    for (int nt = 0; nt < 16; ++nt) acc[nt] = (f32x4){0.f, 0.f, 0.f, 0.f};
    {
        const ushort* g = Wof + (size_t)w * 2048 + lane * 8;
        ushort* ld = SM + w * 2048;
#pragma unroll
        for (int i = 0; i < 4; ++i) gload_lds16(g + i * 512, ld + i * 512);
    }
    __syncthreads();
    for (int c = 0; c < 4; ++c) {
        if (c < 3) {
            const ushort* g = Wof + (size_t)(c + 1) * 16384 + w * 2048 + lane * 8;
            ushort* ld = SM + ((c + 1) & 1) * 16384 + w * 2048;
#pragma unroll
            for (int i = 0; i < 4; ++i) gload_lds16(g + i * 512, ld + i * 512);
        }
        const ushort* buf = SM + (c & 1) * 16384;
#pragma unroll
        for (int n2 = 0; n2 < 4; ++n2)
#pragma unroll
            for (int kt = 0; kt < 8; ++kt) {
                const short8 bf_ = *(const short8*)&buf[(n2 * 8 + kt) * 512 + lane * 8];
                acc[c * 4 + n2] = __builtin_amdgcn_mfma_f32_16x16x32_bf16(af[kt], bf_, acc[c * 4 + n2], 0, 0, 0);
            }
        __syncthreads();
    }

    // residual (+bo +x) then LN1
#pragma unroll
    for (int nt = 0; nt < 16; ++nt) {
        const int d = nt * 16 + l;
        const float bv = bo[d];
#pragma unroll
        for (int r = 0; r < 4; ++r) {
            size_t tok = tok0 + w * 16 + quad * 4 + r;
            acc[nt][r] += bv + x[tok * 256 + d];
        }
    }
    {
        float mu_[4], is_[4];
#pragma unroll
        for (int r = 0; r < 4; ++r) {
            float s = 0.f;
#pragma unroll
            for (int nt = 0; nt < 16; ++nt) s += acc[nt][r];
            s += __shfl_xor(s, 1); s += __shfl_xor(s, 2);
            s += __shfl_xor(s, 4); s += __shfl_xor(s, 8);
            float mu = s * (1.0f / 256.0f);
            float vs = 0.f;
#pragma unroll
            for (int nt = 0; nt < 16; ++nt) { float dd = acc[nt][r] - mu; vs += dd * dd; }
            vs += __shfl_xor(vs, 1); vs += __shfl_xor(vs, 2);
            vs += __shfl_xor(vs, 4); vs += __shfl_xor(vs, 8);
            mu_[r] = mu;
            is_[r] = rsqrtf(vs * (1.0f / 256.0f) + EPS);
        }
        // h = LN1 output: keep fp32 in acc (LN2 residual) + bf16 to SM
#pragma unroll
        for (int nt = 0; nt < 16; ++nt) {
            const int d = nt * 16 + l;
            const float gg = g31[d], bb = b31[d];
#pragma unroll
            for (int r = 0; r < 4; ++r) {
                float hv = (acc[nt][r] - mu_[r]) * is_[r] * gg + bb;
                acc[nt][r] = hv;
                SM[(w * 16 + quad * 4 + r) * ASTR + d] = f2bf(hv);
            }
        }
    }
    __syncthreads();
#pragma unroll
    for (int kt = 0; kt < 8; ++kt)
        af[kt] = *(const short8*)&SM[(w * 16 + l) * ASTR + kt * 32 + quad * 8];
    __syncthreads();   // SM becomes 3-deep panel buffer

    // ---- phase B: MLP, 3-deep counted-vmcnt pipeline, 32 chunks ----
    f32x4 out[16];
#pragma unroll
    for (int nt = 0; nt < 16; ++nt) out[nt] = (f32x4){0.f, 0.f, 0.f, 0.f};

    ushort* Gw = &G[w][0];

    // batch issue: chunk cc panels -> buffer slot s (4 gloads/wave)
    const int wo = w * 1024 + lane * 8;
    const int wl = w * 1024;

    // prologue: batches 0 and 1 in flight; wait for batch 0 only
    {
        const ushort* g1 = W1f + wo;            ushort* l1 = SM + wl;
        const ushort* g2 = W2f + wo;            ushort* l2 = SM + 8192 + wl;
        gload_lds16(g1, l1); gload_lds16(g1 + 512, l1 + 512);
        gload_lds16(g2, l2); gload_lds16(g2 + 512, l2 + 512);
    }
    {
        const ushort* g1 = W1f + 8192 + wo;     ushort* l1 = SM + 16384 + wl;
        const ushort* g2 = W2f + 8192 + wo;     ushort* l2 = SM + 16384 + 8192 + wl;
        gload_lds16(g1, l1); gload_lds16(g1 + 512, l1 + 512);
        gload_lds16(g2, l2); gload_lds16(g2 + 512, l2 + 512);
    }
    asm volatile("s_waitcnt vmcnt(4)" ::: "memory");   // batch 0 landed
    __builtin_amdgcn_s_barrier();
    __builtin_amdgcn_sched_barrier(0);

    for (int c = 0; c < 32; ++c) {
        if (c < 30) {   // issue batch c+2 into slot (c+2)%3
            const int s = (c + 2) % 3;
            const ushort* g1 = W1f + (size_t)(c + 2) * 8192 + wo;
            ushort* l1 = SM + s * 16384 + wl;
            const ushort* g2 = W2f + (size_t)(c + 2) * 8192 + wo;
            ushort* l2 = SM + s * 16384 + 8192 + wl;
            gload_lds16(g1, l1); gload_lds16(g1 + 512, l1 + 512);
            gload_lds16(g2, l2); gload_lds16(g2 + 512, l2 + 512);
        }
        const ushort* WL = SM + (c % 3) * 16384;

        // GEMM1: wave's 16 tok x 32 ff
        f32x4 s0 = {0.f, 0.f, 0.f, 0.f};
        f32x4 s1 = {0.f, 0.f, 0.f, 0.f};
#pragma unroll
        for (int kt = 0; kt < 8; ++kt) {
            const short8 b0 = *(const short8*)&WL[kt * 512 + lane * 8];
            const short8 b1_ = *(const short8*)&WL[(8 + kt) * 512 + lane * 8];
            s0 = __builtin_amdgcn_mfma_f32_16x16x32_bf16(af[kt], b0, s0, 0, 0, 0);
            s1 = __builtin_amdgcn_mfma_f32_16x16x32_bf16(af[kt], b1_, s1, 0, 0, 0);
        }

        // GELU -> wave-private G (no barrier)
#pragma unroll
        for (int n2 = 0; n2 < 2; ++n2) {
            const float bv = B1L[c * 32 + n2 * 16 + l];
#pragma unroll
            for (int r = 0; r < 4; ++r) {
                float v = (n2 ? s1[r] : s0[r]) + bv;
                float au = fabsf(v) * 0.70710678118654752f;
                float t1 = __builtin_amdgcn_rcpf(fmaf(0.3275911f, au, 1.0f));
                float e  = EXP2(au * au * -1.4426950408889634f);
                float p5 = fmaf(fmaf(fmaf(fmaf(1.061405429f, t1, -1.453152027f),
                                t1, 1.421413741f), t1, -0.284496736f), t1, 0.254829592f) * t1;
                float erf_abs = fmaf(-p5, e, 1.0f);
                float gl = fmaf(0.5f * fabsf(v), erf_abs, 0.5f * v);
                Gw[(quad * 4 + r) * GP + n2 * 16 + l] = f2bf(gl);
            }
        }

        // GEMM2: wave's 16 tok x 256 d (K=32)
        const short8 gf = *(const short8*)&Gw[l * GP + quad * 8];
#pragma unroll
        for (int nt = 0; nt < 16; ++nt) {
            const short8 bf_ = *(const short8*)&WL[8192 + nt * 512 + lane * 8];
            out[nt] = __builtin_amdgcn_mfma_f32_16x16x32_bf16(gf, bf_, out[nt], 0, 0, 0);
        }

        // publish slot (c+1)%3: allow only the just-issued batch to remain
        if (c < 30) { asm volatile("s_waitcnt vmcnt(4)" ::: "memory"); }
        else        { asm volatile("s_waitcnt vmcnt(0)" ::: "memory"); }
        __builtin_amdgcn_s_barrier();
        __builtin_amdgcn_sched_barrier(0);
    }

    // ---- residual (h in acc) + bias + LN2 ----
#pragma unroll
    for (int nt = 0; nt < 16; ++nt) {
        const int d = nt * 16 + l;
        const float bv = b2[d];
#pragma unroll
        for (int r = 0; r < 4; ++r)
            out[nt][r] += bv + acc[nt][r];
    }

    float mu_[4], is_[4];
#pragma unroll
    for (int r = 0; r < 4; ++r) {
        float s = 0.f;
#pragma unroll
        for (int nt = 0; nt < 16; ++nt) s += out[nt][r];
        s += __shfl_xor(s, 1); s += __shfl_xor(s, 2);
        s += __shfl_xor(s, 4); s += __shfl_xor(s, 8);
        float mu = s * (1.0f / 256.0f);
        float vs = 0.f;
#pragma unroll
        for (int nt = 0; nt < 16; ++nt) { float dd = out[nt][r] - mu; vs += dd * dd; }
        vs += __shfl_xor(vs, 1); vs += __shfl_xor(vs, 2);
        vs += __shfl_xor(vs, 4); vs += __shfl_xor(vs, 8);
        mu_[r] = mu;
        is_[r] = rsqrtf(vs * (1.0f / 256.0f) + EPS);
    }

#pragma unroll
    for (int nt = 0; nt < 16; ++nt) {
        const int d = nt * 16 + l;
        const float gg = g41[d], bb = b41[d];
#pragma unroll
        for (int r = 0; r < 4; ++r) {
            size_t tok = tok0 + w * 16 + quad * 4 + r;
            io[tok * 256 + d] = (out[nt][r] - mu_[r]) * is_[r] * gg + bb;
        }
    }
}

// ---------------------------------------------------------------------------
extern "C" void kernel_launch(void* const* d_in, const int* in_sizes, int n_in,
                              void* d_out, int out_size, void* d_ws, size_t ws_size,
                              hipStream_t stream)
{
    const float* x   = (const float*)d_in[0];
    const float* Wq  = (const float*)d_in[1];
    const float* bq  = (const float*)d_in[2];
    const float* Wk  = (const float*)d_in[3];
    const float* bk  = (const float*)d_in[4];
    const float* Wv  = (const float*)d_in[5];
    const float* bv  = (const float*)d_in[6];
    const float* Wo  = (const float*)d_in[7];
    const float* bo  = (const float*)d_in[8];
    const float* g31 = (const float*)d_in[9];
    const float* b31 = (const float*)d_in[10];
    const float* W1  = (const float*)d_in[11];
    const float* b1  = (const float*)d_in[12];
    const float* W2  = (const float*)d_in[13];
    const float* b2  = (const float*)d_in[14];
    const float* g41 = (const float*)d_in[15];
    const float* b41 = (const float*)d_in[16];

    float* out = (float*)d_out;

    // workspace layout (ushort units):
    const size_t HALF = (size_t)BATCH * SEG * DMODEL;   // 4,194,304
    ushort* qbuf = (ushort*)d_ws;            // row  [b][h][seg][32]
    ushort* kbuf = qbuf + HALF;              // row (pre-scaled by sc*log2e)
    ushort* qt   = kbuf + HALF;              // transposed [b][h][32][1024]
    ushort* vt   = qt + HALF;                // transposed
    ushort* abuf = vt + HALF;                // NTOK*256
    ushort* Wqf  = abuf + 2 * HALF;
    ushort* Wkf  = Wqf + 65536;
    ushort* Wvf  = Wkf + 65536;
    ushort* Wof  = Wvf + 65536;
    ushort* W1f  = Wof + 65536;              // 262144
    ushort* W2f  = W1f + 262144;             // 262144

    // 0. weight fragmentization: ONE launch for all 6 weights
    wfrag_all_kernel<<<384, 256, 0, stream>>>(Wq, Wk, Wv, Wo, W1, W2,
                                              Wqf, Wkf, Wvf, Wof, W1f, W2f);

    // 1. fused QKV projection, balanced 3-way grid (Q half-0, K/V half-1)
    qkv_mfma_kernel<<<768, 256, 0, stream>>>(x, Wqf, bq, Wkf, bk, Wvf, bv,
                                             qbuf, kbuf, qt, vt);
    // 2. two-stage attention (staged K/V + T14 early loads) -> bf16 [tok][256]
    attn_mfma_kernel<<<2 * BATCH * NH * (SEG / 64), 256, 0, stream>>>(qbuf, kbuf, qt, vt, abuf);
    // 3. FUSED proj+LN1+MLP+LN2: 256 blocks x 128 tok, 1 block/CU, weights
    //    streamed once per CU with 3-deep counted-vmcnt panel pipeline
    proj_mlp_kernel<<<NTOK / 128, 512, 0, stream>>>(abuf, Wof, bo, x, g31, b31,
                                                    W1f, b1, W2f, b2, g41, b41, out);
}

// Round 12
// 265.023 us; speedup vs baseline: 1.0146x; 1.0146x over previous
//
#include <hip/hip_runtime.h>
#include <hip/hip_bf16.h>
#include <math.h>

// Problem constants
#define BATCH 16
#define SEG 1024
#define DMODEL 256
#define NH 8
#define DK 32
#define DFF 1024
#define NTOK (BATCH * 2 * SEG)        // 32768 tokens
#define EPS 1e-5f

typedef __attribute__((ext_vector_type(8))) short short8;
typedef __attribute__((ext_vector_type(4))) short short4b;
typedef __attribute__((ext_vector_type(4))) float f32x4;

#if __has_builtin(__builtin_amdgcn_exp2f)
#define EXP2(x) __builtin_amdgcn_exp2f(x)
#else
#define EXP2(x) __expf((x) * 0.6931471805599453f)
#endif

__device__ __forceinline__ ushort f2bf(float x) {
    union { float f; unsigned u; } a; a.f = x;
    unsigned r = a.u + 0x7fffu + ((a.u >> 16) & 1u);   // RNE
    return (ushort)(r >> 16);
}

// async global -> LDS, 16 B per lane. lds base must be wave-uniform;
// HW writes lane i's 16 B at lds_base + i*16.
typedef const __attribute__((address_space(1))) unsigned gas_u32;
typedef __attribute__((address_space(3))) unsigned las_u32;
__device__ __forceinline__ void gload_lds16(const ushort* g, ushort* l) {
    __builtin_amdgcn_global_load_lds((gas_u32*)g, (las_u32*)l, 16, 0, 0);
}

// ---------------------------------------------------------------------------
// Merged weight fragmentizer: all 6 weights in ONE launch (384 blocks).
// W[K x N] fp32 row-major -> bf16 B-fragment-linear.
// order 0: frag index = nt*KT_+kt ; order 1: frag index = kt*NT_+nt (W2)
// ---------------------------------------------------------------------------
__global__ __launch_bounds__(256) void wfrag_all_kernel(
    const float* __restrict__ Wq, const float* __restrict__ Wk,
    const float* __restrict__ Wv, const float* __restrict__ Wo,
    const float* __restrict__ W1, const float* __restrict__ W2,
    ushort* __restrict__ Wqf, ushort* __restrict__ Wkf,
    ushort* __restrict__ Wvf, ushort* __restrict__ Wof,
    ushort* __restrict__ W1f, ushort* __restrict__ W2f)
{
    const int blk = blockIdx.x;          // 0..383
    const float* src; ushort* dst; int K, N, order, base;
    if (blk < 32)       { src = Wq; dst = Wqf; K = 256;  N = 256;  order = 0; base = 0;   }
    else if (blk < 64)  { src = Wk; dst = Wkf; K = 256;  N = 256;  order = 0; base = 32;  }
    else if (blk < 96)  { src = Wv; dst = Wvf; K = 256;  N = 256;  order = 0; base = 64;  }
    else if (blk < 128) { src = Wo; dst = Wof; K = 256;  N = 256;  order = 0; base = 96;  }
    else if (blk < 256) { src = W1; dst = W1f; K = 256;  N = 1024; order = 0; base = 128; }
    else                { src = W2; dst = W2f; K = 1024; N = 256;  order = 1; base = 256; }
    const int tid = (blk - base) * 256 + threadIdx.x;
    const int KT_ = K >> 5, NT_ = N >> 4;
    const int lane = tid & 63;
    const int frag = tid >> 6;
    int kt, nt;
    if (order) { kt = frag / NT_; nt = frag % NT_; }
    else       { nt = frag / KT_; kt = frag % KT_; }
    const int quad = lane >> 4, l = lane & 15;
    const float* s = src + (size_t)(kt * 32 + quad * 8) * N + nt * 16 + l;
    short8 v;
#pragma unroll
    for (int j = 0; j < 8; j++) v[j] = (short)f2bf(s[(size_t)j * N]);
    *(short8*)&dst[(size_t)tid * 8] = v;
}

#define ASTR 264   // LDS A row stride (bf16 units) - conflict-free ds_read_b128

// ---------------------------------------------------------------------------
// Dense pass helper: 4 chunks of 64 out-dims; W panel DOUBLE-BUFFERED in LDS.
// WL must hold 2 x 8192 ushorts (fits in 64*ASTR = 16896).
// ---------------------------------------------------------------------------
__device__ __forceinline__ void dense256_pass(
    const ushort* __restrict__ Wf, ushort* WL, const short8* af,
    f32x4* acc, int t, int w, int lane)
{
#pragma unroll
    for (int nt = 0; nt < 16; ++nt) acc[nt] = (f32x4){0.f, 0.f, 0.f, 0.f};
    // prologue: stage chunk 0 into buffer 0
    {
        const ushort* g = Wf + (size_t)w * 4096 + lane * 8;
        ushort* ld = WL + w * 4096;
#pragma unroll
        for (int i = 0; i < 8; ++i) gload_lds16(g + i * 512, ld + i * 512);
    }
    __syncthreads();
    for (int c = 0; c < 4; ++c) {
        if (c < 3) {    // prefetch next chunk into the other buffer
            const ushort* g = Wf + (size_t)(c + 1) * 16384 + w * 4096 + lane * 8;
            ushort* ld = WL + ((c + 1) & 1) * 8192 + w * 4096;
#pragma unroll
            for (int i = 0; i < 8; ++i) gload_lds16(g + i * 512, ld + i * 512);
        }
        const ushort* buf = WL + (c & 1) * 8192;
#pragma unroll
        for (int n2 = 0; n2 < 4; ++n2)
#pragma unroll
            for (int kt = 0; kt < 8; ++kt) {
                const short8 bf_ = *(const short8*)&buf[(n2 * 8 + kt) * 512 + lane * 8];
                acc[c * 4 + n2] = __builtin_amdgcn_mfma_f32_16x16x32_bf16(af[kt], bf_, acc[c * 4 + n2], 0, 0, 0);
            }
        __syncthreads();   // drains prefetch (already landed under compute)
    }
}

// ---------------------------------------------------------------------------
// Kernel 1: fused QKV projection, BALANCED 3-way grid (768 blocks, 1 dense
// pass each). which=0: Q over half-0 tokens -> qbuf(row)+qt(transp);
// which=1: K over half-1 tokens -> kbuf(row, PRE-SCALED by 1/sqrt(32)*log2e);
// which=2: V over half-1 tokens -> vt(transp).
// ---------------------------------------------------------------------------
__global__ __launch_bounds__(256) void qkv_mfma_kernel(
    const float* __restrict__ x,
    const ushort* __restrict__ Wqf, const float* __restrict__ bq,
    const ushort* __restrict__ Wkf, const float* __restrict__ bk,
    const ushort* __restrict__ Wvf, const float* __restrict__ bv,
    ushort* __restrict__ qbuf, ushort* __restrict__ kbuf,
    ushort* __restrict__ qt, ushort* __restrict__ vt)
{
    __shared__ __align__(16) ushort SM[64 * ASTR];   // union: A-stage / dbuf panels / transpose
    const int bid = blockIdx.x;          // 0..767
    const int which = bid >> 8;          // 0=Q, 1=K, 2=V
    const int sub = bid & 255;
    const int b = sub >> 4, ti = sub & 15;
    const int half = (which == 0) ? 0 : 1;
    const int t = threadIdx.x;
    const int w = t >> 6, lane = t & 63, l = lane & 15, quad = lane >> 4;

    // stage x tile (fp32 -> bf16)
    const float* xrow = x + ((size_t)b * 2048 + (size_t)half * 1024 + ti * 64) * 256;
#pragma unroll
    for (int p = 0; p < 16; ++p) {
        int ch = t + 256 * p;
        int row = ch >> 6, c4 = ch & 63;
        float4 v = *(const float4*)&xrow[row * 256 + c4 * 4];
        uint2 pk;
        pk.x = (unsigned)f2bf(v.x) | ((unsigned)f2bf(v.y) << 16);
        pk.y = (unsigned)f2bf(v.z) | ((unsigned)f2bf(v.w) << 16);
        *(uint2*)&SM[row * ASTR + c4 * 4] = pk;
    }
    __syncthreads();

    short8 af[8];
#pragma unroll
    for (int kt = 0; kt < 8; ++kt)
        af[kt] = *(const short8*)&SM[(w * 16 + l) * ASTR + kt * 32 + quad * 8];
    __syncthreads();   // SM becomes weight-panel / transpose buffer

    const ushort* Wf  = (which == 0) ? Wqf : (which == 1 ? Wkf : Wvf);
    const float* bias = (which == 0) ? bq  : (which == 1 ? bk  : bv);
    // kbuf pre-scaled: it is only ever an S-operand (stage0 K, stage1 Q)
    const float kscale = (which == 1) ? 0.25503472f : 1.0f;  // sc*log2e

    f32x4 acc[16];
    dense256_pass(Wf, SM, af, acc, t, w, lane);

    ushort bfv[16][4];
#pragma unroll
    for (int nt = 0; nt < 16; ++nt) {
        const float bb = bias[nt * 16 + l];
#pragma unroll
        for (int r = 0; r < 4; ++r) bfv[nt][r] = f2bf((acc[nt][r] + bb) * kscale);
    }

    if (which <= 1) {                 // rowout: Q or K
        ushort* obuf = which ? kbuf : qbuf;
#pragma unroll
        for (int nt = 0; nt < 16; ++nt) {
            const int h = nt >> 1, e = (nt & 1) * 16 + l;
#pragma unroll
            for (int r = 0; r < 4; ++r) {
                int tok = ti * 64 + w * 16 + quad * 4 + r;
                obuf[(((size_t)b * 8 + h) * SEG + tok) * 32 + e] = bfv[nt][r];
            }
        }
    }
    if (which != 1) {                 // trout: Q or V
        ushort* tb = which ? vt : qt;
        // LDS bounce transpose: SM_T[d][ltok], stride 66
#pragma unroll
        for (int nt = 0; nt < 16; ++nt)
#pragma unroll
            for (int r = 0; r < 4; ++r)
                SM[(nt * 16 + l) * 66 + w * 16 + quad * 4 + r] = bfv[nt][r];
        __syncthreads();
        const int d = t, hh = t >> 5, e = t & 31;
        ushort* dr = tb + (((size_t)b * 8 + hh) * 32 + e) * 1024 + ti * 64;
#pragma unroll
        for (int j = 0; j < 8; ++j) {
            uint2 v;
            v.x = *(const unsigned*)&SM[d * 66 + j * 8];
            v.y = *(const unsigned*)&SM[d * 66 + j * 8 + 2];
            unsigned z0 = *(const unsigned*)&SM[d * 66 + j * 8 + 4];
            unsigned z1 = *(const unsigned*)&SM[d * 66 + j * 8 + 6];
            *(uint4*)&dr[j * 8] = make_uint4(v.x, v.y, z0, z1);
        }
    }
}

// ---------------------------------------------------------------------------
// Kernel 2: two-stage attention (staged K/V, lane-permuted K write, KP=40/
// VP=132) + T14 async-STAGE split. NO setprio: R11 showed the setprio
// variant fails the post-timing determinism tripwire (m152 lesson).
// ---------------------------------------------------------------------------
#define KTILE 128
#define KP 40       // Kl row stride
#define VP 132      // Vl row stride over keys

__global__ __launch_bounds__(256) void attn_mfma_kernel(
    const ushort* __restrict__ qbuf, const ushort* __restrict__ kbuf,
    const ushort* __restrict__ qt, const ushort* __restrict__ vt,
    ushort* __restrict__ abuf)
{
    __shared__ __align__(16) ushort Kl[KTILE * KP];   // 10240 B; reused as O-bounce
    __shared__ __align__(16) ushort Vl[32 * VP];      //  8448 B

    const int bid   = blockIdx.x;        // 0 .. 4095
    const int sbh   = bid & 255;         // (stage,b,h) in low bits
    const int qtile = bid >> 8;          // 0..15
    const int stage = sbh >> 7;
    const int b     = (sbh >> 3) & 15;
    const int h     = sbh & 7;

    const ushort* Qm = stage ? kbuf : qbuf;   // queries, row [seg][32]
    const ushort* Km = stage ? qbuf : kbuf;   // keys, row
    const ushort* Vt = stage ? qt : vt;       // values, transposed [32][1024]
    const size_t bh = ((size_t)b * 8 + h) * SEG * 32;

    const int t    = threadIdx.x;
    const int w    = t >> 6;
    const int lane = t & 63;
    const int l    = lane & 15;
    const int quad = lane >> 4;

    // Q fragment (B-operand of S^T mfma): lane holds q-col l, k=quad*8+j
    const int qrow = qtile * 64 + w * 16 + l;
    const short8 qf = *(const short8*)&Qm[bh + (size_t)qrow * 32 + quad * 8];

    f32x4 o0 = {0.f, 0.f, 0.f, 0.f};     // O^T block d=0..15  (row=d, col=q=l)
    f32x4 o1 = {0.f, 0.f, 0.f, 0.f};     // O^T block d=16..31
    f32x4 o2 = {0.f, 0.f, 0.f, 0.f};     // ones-row: column sums of quantized P
    const short4b ones = {(short)0x3F80, (short)0x3F80, (short)0x3F80, (short)0x3F80};

    // per-thread staging chunk mappings (fixed across tiles)
    const int ch0 = t, ch1 = t + 256;
    // K: lane-permuted (8-lane phase = 8 consecutive rows, bank stride 20)
    const int kr0 = ((ch0 >> 6) << 4) | (ch0 & 15), kp0 = (ch0 >> 4) & 3;
    const int kr1 = ((ch1 >> 6) << 4) | (ch1 & 15), kp1 = (ch1 >> 4) & 3;
    const int vd0 = ch0 >> 4, vc0 = ch0 & 15;
    const int vd1 = ch1 >> 4, vc1 = ch1 & 15;
    const ushort* Kgb = &Km[bh];
    const ushort* Vgb = &Vt[bh];

    // prologue: load tile 0 into registers
    short8 rk0 = *(const short8*)&Kgb[(size_t)kr0 * 32 + kp0 * 8];
    short8 rk1 = *(const short8*)&Kgb[(size_t)kr1 * 32 + kp1 * 8];
    short8 rv0 = *(const short8*)&Vgb[(size_t)vd0 * 1024 + vc0 * 8];
    short8 rv1 = *(const short8*)&Vgb[(size_t)vd1 * 1024 + vc1 * 8];

    for (int tile = 0; tile < 8; ++tile) {
        __syncthreads();   // prev-tile readers done
        *(short8*)&Kl[kr0 * KP + kp0 * 8] = rk0;
        *(short8*)&Kl[kr1 * KP + kp1 * 8] = rk1;
        *(short8*)&Vl[vd0 * VP + vc0 * 8] = rv0;
        *(short8*)&Vl[vd1 * VP + vc1 * 8] = rv1;
        __syncthreads();   // tile data visible

        if (tile < 7) {    // T14: issue next-tile loads before compute
            const size_t ko = (size_t)(tile + 1) * KTILE * 32;
            const size_t vo = (size_t)(tile + 1) * KTILE;
            rk0 = *(const short8*)&Kgb[ko + (size_t)kr0 * 32 + kp0 * 8];
            rk1 = *(const short8*)&Kgb[ko + (size_t)kr1 * 32 + kp1 * 8];
            rv0 = *(const short8*)&Vgb[vo + (size_t)vd0 * 1024 + vc0 * 8];
            rv1 = *(const short8*)&Vgb[vo + (size_t)vd1 * 1024 + vc1 * 8];
        }

#pragma unroll
        for (int kb = 0; kb < 8; ++kb) {
            // A-frag of S^T: key row kb*16+l, k=quad*8+j
            const short8 kf = *(const short8*)&Kl[(kb * 16 + l) * KP + quad * 8];
            f32x4 z = {0.f, 0.f, 0.f, 0.f};
            f32x4 sc = __builtin_amdgcn_mfma_f32_16x16x32_bf16(kf, qf, z, 0, 0, 0);
            // native exp2 (scale*log2e folded into K); truncate-pack to bf16
            union { float f; unsigned u; } a0, a1, a2, a3;
            a0.f = EXP2(sc[0]); a1.f = EXP2(sc[1]);
            a2.f = EXP2(sc[2]); a3.f = EXP2(sc[3]);
            unsigned lo = __builtin_amdgcn_perm(a1.u, a0.u, 0x07060302u);
            unsigned hi = __builtin_amdgcn_perm(a3.u, a2.u, 0x07060302u);
            union { uint2 u; short4b s; } pk; pk.u = make_uint2(lo, hi);
            // A-frags of O^T: V^T rows d=l / 16+l, k=key=quad*4+i
            const short4b vf0 = *(const short4b*)&Vl[l * VP + kb * 16 + quad * 4];
            const short4b vf1 = *(const short4b*)&Vl[(16 + l) * VP + kb * 16 + quad * 4];
            o0 = __builtin_amdgcn_mfma_f32_16x16x16bf16_1k(vf0, pk.s, o0, 0, 0, 0);
            o1 = __builtin_amdgcn_mfma_f32_16x16x16bf16_1k(vf1, pk.s, o1, 0, 0, 0);
            o2 = __builtin_amdgcn_mfma_f32_16x16x16bf16_1k(ones, pk.s, o2, 0, 0, 0);
        }
    }

    // ---- normalize: o2[0] = sum over all keys of quantized P for q=l ----
    const float inv = 1.0f / o2[0];
#pragma unroll
    for (int r = 0; r < 4; ++r) { o0[r] *= inv; o1[r] *= inv; }

    // ---- O^T -> LDS bounce (reuse Kl) -> coalesced bf16 store ----
    __syncthreads();
    ushort* Ob = &Kl[w * 16 * 40];        // per-wave [q=16][d=32] pad 40
#pragma unroll
    for (int r = 0; r < 4; ++r) {
        Ob[l * 40 + quad * 4 + r]      = f2bf(o0[r]);
        Ob[l * 40 + 16 + quad * 4 + r] = f2bf(o1[r]);
    }
    __syncthreads();
    const int q = lane >> 2, part = lane & 3;
    const short8 ov = *(const short8*)&Ob[q * 40 + part * 8];
    const int tok = qtile * 64 + w * 16 + q;
    *(short8*)&abuf[((size_t)b * 2 * SEG + (size_t)stage * SEG + tok) * 256 + h * 32 + part * 8] = ov;
}

// ---------------------------------------------------------------------------
// Kernel 3: FUSED out-proj + LN1 + MLP + LN2 (Round-9 measured best: 85.1us).
// Per 64-token block:
//   phase A (proj): abuf -> SM A-stage; dense256_pass(Wo); +bo +x residual;
//     LN1 -> h kept fp32 in registers (LN2 residual) AND written bf16 to SM
//     for mlp A-fragments. h NEVER touches global memory.
//   phase B (mlp): token-only wave split (wave w = 16 tok x full 32-ff
//     chunk) -> GELU->G->GEMM2 handoff is WAVE-PRIVATE (lgkmcnt, no
//     barrier). ONE barrier per chunk (panel swap).
//   LN2 fully within-wave, store final out.
// NOTE (R6/R10 lesson): the chunk loop is bound by a serial per-chunk
// latency chain overlapped by the 2 resident blocks/CU; 1-block/CU or
// deeper prefetch variants measured SLOWER. Do not reduce residency.
// ---------------------------------------------------------------------------
#define GP 40

__global__ __launch_bounds__(256, 2) void proj_mlp_kernel(
    const ushort* __restrict__ abuf, const ushort* __restrict__ Wof,
    const float* __restrict__ bo, const float* __restrict__ x,
    const float* __restrict__ g31, const float* __restrict__ b31,
    const ushort* __restrict__ W1f, const float* __restrict__ b1,
    const ushort* __restrict__ W2f, const float* __restrict__ b2,
    const float* __restrict__ g41, const float* __restrict__ b41,
    float* __restrict__ io)
{
    __shared__ __align__(16) ushort SM[2 * 16384];   // A-stage / panel dbuf
    __shared__ __align__(16) ushort G[4][16 * GP];   // per-wave private GELU buf
    __shared__ __align__(16) float B1L[DFF];          // staged b1
    const int bid = blockIdx.x;          // 0..511
    const size_t tok0 = (size_t)bid * 64;
    const int t = threadIdx.x;
    const int w = t >> 6, lane = t & 63, l = lane & 15, quad = lane >> 4;

    // ---- phase A: stage abuf tile into SM (ASTR layout) + b1 ----
#pragma unroll
    for (int p = 0; p < 8; ++p) {
        int ch = t + 256 * p;
        int row = ch >> 5, c8 = ch & 31;
        *(short8*)&SM[row * ASTR + c8 * 8] = *(const short8*)&abuf[(tok0 + row) * 256 + c8 * 8];
    }
    *(float4*)&B1L[t * 4] = *(const float4*)&b1[t * 4];
    __syncthreads();

    short8 af[8];
#pragma unroll
    for (int kt = 0; kt < 8; ++kt)
        af[kt] = *(const short8*)&SM[(w * 16 + l) * ASTR + kt * 32 + quad * 8];
    __syncthreads();

    f32x4 acc[16];
    dense256_pass(Wof, SM, af, acc, t, w, lane);

    // residual (+bo +x) then LN1
#pragma unroll
    for (int nt = 0; nt < 16; ++nt) {
        const int d = nt * 16 + l;
        const float bv = bo[d];
#pragma unroll
        for (int r = 0; r < 4; ++r) {
            size_t tok = tok0 + w * 16 + quad * 4 + r;
            acc[nt][r] += bv + x[tok * 256 + d];
        }
    }
    {
        float mu_[4], is_[4];
#pragma unroll
        for (int r = 0; r < 4; ++r) {
            float s = 0.f;
#pragma unroll
            for (int nt = 0; nt < 16; ++nt) s += acc[nt][r];
            s += __shfl_xor(s, 1); s += __shfl_xor(s, 2);
            s += __shfl_xor(s, 4); s += __shfl_xor(s, 8);
            float mu = s * (1.0f / 256.0f);
            float vs = 0.f;
#pragma unroll
            for (int nt = 0; nt < 16; ++nt) { float dd = acc[nt][r] - mu; vs += dd * dd; }
            vs += __shfl_xor(vs, 1); vs += __shfl_xor(vs, 2);
            vs += __shfl_xor(vs, 4); vs += __shfl_xor(vs, 8);
            mu_[r] = mu;
            is_[r] = rsqrtf(vs * (1.0f / 256.0f) + EPS);
        }
        // h = LN1 output: keep fp32 in acc (hres) + write bf16 to SM
#pragma unroll
        for (int nt = 0; nt < 16; ++nt) {
            const int d = nt * 16 + l;
            const float gg = g31[d], bb = b31[d];
#pragma unroll
            for (int r = 0; r < 4; ++r) {
                float hv = (acc[nt][r] - mu_[r]) * is_[r] * gg + bb;
                acc[nt][r] = hv;
                SM[(w * 16 + quad * 4 + r) * ASTR + d] = f2bf(hv);
            }
        }
    }
    __syncthreads();
    // reload A-fragments = h bf16
#pragma unroll
    for (int kt = 0; kt < 8; ++kt)
        af[kt] = *(const short8*)&SM[(w * 16 + l) * ASTR + kt * 32 + quad * 8];
    __syncthreads();   // SM becomes panel double-buffer

    // ---- phase B: MLP, token-only wave split, 1 barrier/chunk ----
    f32x4 out[16];
#pragma unroll
    for (int nt = 0; nt < 16; ++nt) out[nt] = (f32x4){0.f, 0.f, 0.f, 0.f};

    ushort* Gw = &G[w][0];

    // prologue: stage chunk 0 panels (W1 -> [0..8191], W2 -> [8192..16383])
    {
        const ushort* g1 = W1f + w * 2048 + lane * 8;
        const ushort* g2 = W2f + w * 2048 + lane * 8;
        ushort* l1 = SM + w * 2048;
        ushort* l2 = SM + 8192 + w * 2048;
#pragma unroll
        for (int i = 0; i < 4; ++i) {
            gload_lds16(g1 + i * 512, l1 + i * 512);
            gload_lds16(g2 + i * 512, l2 + i * 512);
        }
    }
    __syncthreads();

    for (int c = 0; c < 32; ++c) {
        if (c < 31) {   // prefetch chunk c+1 into the other buffer
            const int nb = (c + 1) & 1;
            const ushort* g1 = W1f + (size_t)(c + 1) * 8192 + w * 2048 + lane * 8;
            ushort* l1 = SM + nb * 16384 + w * 2048;
            const ushort* g2 = W2f + (size_t)(c + 1) * 8192 + w * 2048 + lane * 8;
            ushort* l2 = SM + nb * 16384 + 8192 + w * 2048;
#pragma unroll
            for (int i = 0; i < 4; ++i) {
                gload_lds16(g1 + i * 512, l1 + i * 512);
                gload_lds16(g2 + i * 512, l2 + i * 512);
            }
        }
        const ushort* WL = SM + (c & 1) * 16384;

        // GEMM1: wave's 16 tok x 32 ff (both ff tiles of the chunk)
        f32x4 s0 = {0.f, 0.f, 0.f, 0.f};
        f32x4 s1 = {0.f, 0.f, 0.f, 0.f};
#pragma unroll
        for (int kt = 0; kt < 8; ++kt) {
            const short8 b0 = *(const short8*)&WL[kt * 512 + lane * 8];
            const short8 b1_ = *(const short8*)&WL[(8 + kt) * 512 + lane * 8];
            s0 = __builtin_amdgcn_mfma_f32_16x16x32_bf16(af[kt], b0, s0, 0, 0, 0);
            s1 = __builtin_amdgcn_mfma_f32_16x16x32_bf16(af[kt], b1_, s1, 0, 0, 0);
        }

        // GELU -> wave-private G (no barrier: cross-lane within wave only)
#pragma unroll
        for (int n2 = 0; n2 < 2; ++n2) {
            const float bv = B1L[c * 32 + n2 * 16 + l];
#pragma unroll
            for (int r = 0; r < 4; ++r) {
                float v = (n2 ? s1[r] : s0[r]) + bv;
                float au = fabsf(v) * 0.70710678118654752f;
                float t1 = __builtin_amdgcn_rcpf(fmaf(0.3275911f, au, 1.0f));
                float e  = EXP2(au * au * -1.4426950408889634f);
                float p5 = fmaf(fmaf(fmaf(fmaf(1.061405429f, t1, -1.453152027f),
                                t1, 1.421413741f), t1, -0.284496736f), t1, 0.254829592f) * t1;
                float erf_abs = fmaf(-p5, e, 1.0f);
                float gl = fmaf(0.5f * fabsf(v), erf_abs, 0.5f * v);
                Gw[(quad * 4 + r) * GP + n2 * 16 + l] = f2bf(gl);
            }
        }

        // GEMM2: wave's 16 tok x 256 d over this 32-ff chunk (K=32)
        const short8 gf = *(const short8*)&Gw[l * GP + quad * 8];
#pragma unroll
        for (int nt = 0; nt < 16; ++nt) {
            const short8 bf_ = *(const short8*)&WL[8192 + nt * 512 + lane * 8];
            out[nt] = __builtin_amdgcn_mfma_f32_16x16x32_bf16(gf, bf_, out[nt], 0, 0, 0);
        }
        __syncthreads();   // panel swap point (drains prefetch)
    }

    // ---- residual (hres in acc, register-aligned) + bias + LN2 ----
#pragma unroll
    for (int nt = 0; nt < 16; ++nt) {
        const int d = nt * 16 + l;
        const float bv = b2[d];
#pragma unroll
        for (int r = 0; r < 4; ++r)
            out[nt][r] += bv + acc[nt][r];
    }

    float mu_[4], is_[4];
#pragma unroll
    for (int r = 0; r < 4; ++r) {
        float s = 0.f;
#pragma unroll
        for (int nt = 0; nt < 16; ++nt) s += out[nt][r];
        s += __shfl_xor(s, 1); s += __shfl_xor(s, 2);
        s += __shfl_xor(s, 4); s += __shfl_xor(s, 8);
        float mu = s * (1.0f / 256.0f);
        float vs = 0.f;
#pragma unroll
        for (int nt = 0; nt < 16; ++nt) { float dd = out[nt][r] - mu; vs += dd * dd; }
        vs += __shfl_xor(vs, 1); vs += __shfl_xor(vs, 2);
        vs += __shfl_xor(vs, 4); vs += __shfl_xor(vs, 8);
        mu_[r] = mu;
        is_[r] = rsqrtf(vs * (1.0f / 256.0f) + EPS);
    }

#pragma unroll
    for (int nt = 0; nt < 16; ++nt) {
        const int d = nt * 16 + l;
        const float gg = g41[d], bb = b41[d];
#pragma unroll
        for (int r = 0; r < 4; ++r) {
            size_t tok = tok0 + w * 16 + quad * 4 + r;
            io[tok * 256 + d] = (out[nt][r] - mu_[r]) * is_[r] * gg + bb;
        }
    }
}

// ---------------------------------------------------------------------------
extern "C" void kernel_launch(void* const* d_in, const int* in_sizes, int n_in,
                              void* d_out, int out_size, void* d_ws, size_t ws_size,
                              hipStream_t stream)
{
    const float* x   = (const float*)d_in[0];
    const float* Wq  = (const float*)d_in[1];
    const float* bq  = (const float*)d_in[2];
    const float* Wk  = (const float*)d_in[3];
    const float* bk  = (const float*)d_in[4];
    const float* Wv  = (const float*)d_in[5];
    const float* bv  = (const float*)d_in[6];
    const float* Wo  = (const float*)d_in[7];
    const float* bo  = (const float*)d_in[8];
    const float* g31 = (const float*)d_in[9];
    const float* b31 = (const float*)d_in[10];
    const float* W1  = (const float*)d_in[11];
    const float* b1  = (const float*)d_in[12];
    const float* W2  = (const float*)d_in[13];
    const float* b2  = (const float*)d_in[14];
    const float* g41 = (const float*)d_in[15];
    const float* b41 = (const float*)d_in[16];

    float* out = (float*)d_out;

    // workspace layout (ushort units):
    const size_t HALF = (size_t)BATCH * SEG * DMODEL;   // 4,194,304
    ushort* qbuf = (ushort*)d_ws;            // row  [b][h][seg][32]
    ushort* kbuf = qbuf + HALF;              // row (pre-scaled by sc*log2e)
    ushort* qt   = kbuf + HALF;              // transposed [b][h][32][1024]
    ushort* vt   = qt + HALF;                // transposed
    ushort* abuf = vt + HALF;                // NTOK*256
    ushort* Wqf  = abuf + 2 * HALF;
    ushort* Wkf  = Wqf + 65536;
    ushort* Wvf  = Wkf + 65536;
    ushort* Wof  = Wvf + 65536;
    ushort* W1f  = Wof + 65536;              // 262144
    ushort* W2f  = W1f + 262144;             // 262144

    // 0. weight fragmentization: ONE launch for all 6 weights
    wfrag_all_kernel<<<384, 256, 0, stream>>>(Wq, Wk, Wv, Wo, W1, W2,
                                              Wqf, Wkf, Wvf, Wof, W1f, W2f);

    // 1. fused QKV projection, balanced 3-way grid (Q half-0, K/V half-1)
    qkv_mfma_kernel<<<768, 256, 0, stream>>>(x, Wqf, bq, Wkf, bk, Wvf, bv,
                                             qbuf, kbuf, qt, vt);
    // 2. two-stage attention (staged K/V + T14 early loads) -> bf16 [tok][256]
    attn_mfma_kernel<<<2 * BATCH * NH * (SEG / 64), 256, 0, stream>>>(qbuf, kbuf, qt, vt, abuf);
    // 3. FUSED out-proj + LN1 + MLP + LN2 (h never hits HBM; 1 barrier/chunk)
    proj_mlp_kernel<<<NTOK / 64, 256, 0, stream>>>(abuf, Wof, bo, x, g31, b31,
                                                   W1f, b1, W2f, b2, g41, b41, out);
}